// Round 10
// baseline (230.685 us; speedup 1.0000x reference)
//
#include <hip/hip_runtime.h>

#define FIN 256
#define H1 8
#define C1 16
#define D1 128   // H1*C1
#define D2 40
#define D2P 48

#define BW_LOG 8
#define BWIDTH 256           // nodes per bucket
#define B1 128               // phase-1 blocks

typedef float f32x4 __attribute__((ext_vector_type(4)));
typedef short bf16x8 __attribute__((ext_vector_type(8)));

static __device__ __forceinline__ float lrelu(float x){ return fmaxf(x, 0.2f*x); }
static __device__ __forceinline__ float elu(float x){ return x > 0.f ? x : __expf(x) - 1.f; }
static __device__ __forceinline__ unsigned short f2bf(float f){      // RNE bf16
  unsigned u = __float_as_uint(f);
  return (unsigned short)((u + 0x7fffu + ((u >> 16) & 1u)) >> 16);
}
static __device__ __forceinline__ float bf_lo(unsigned v){ return __uint_as_float(v << 16); }
static __device__ __forceinline__ float bf_hi(unsigned v){ return __uint_as_float(v & 0xffff0000u); }
static __device__ __forceinline__ bf16x8 pack_bf8(float4 a, float4 b){
  bf16x8 r;
  r[0]=(short)f2bf(a.x); r[1]=(short)f2bf(a.y); r[2]=(short)f2bf(a.z); r[3]=(short)f2bf(a.w);
  r[4]=(short)f2bf(b.x); r[5]=(short)f2bf(b.y); r[6]=(short)f2bf(b.z); r[7]=(short)f2bf(b.w);
  return r;
}

// ---------------- CSR build: deterministic bucket sort ----------------
__global__ __launch_bounds__(256) void p1count_k(const int* __restrict__ dst, int E, int NB,
                                                 int* __restrict__ blockHist){
  extern __shared__ int hist[];
  int blk = blockIdx.x, t = threadIdx.x;
  for (int i = t; i < NB; i += 256) hist[i] = 0;
  __syncthreads();
  int CH = (E + B1 - 1) / B1;
  int lo = blk*CH, hi = min(E, lo + CH);
  for (int i = lo + t; i < hi; i += 256)
    atomicAdd(&hist[dst[i] >> BW_LOG], 1);
  __syncthreads();
  for (int b = t; b < NB; b += 256) blockHist[b*B1 + blk] = hist[b];
}

__global__ __launch_bounds__(B1) void bscan_k(const int* __restrict__ blockHist,
                                              int* __restrict__ wOff, int* __restrict__ bucketCnt){
  __shared__ int s[B1];
  int b = blockIdx.x, t = threadIdx.x;
  int v = blockHist[b*B1 + t];
  s[t] = v; __syncthreads();
  for (int o = 1; o < B1; o <<= 1){
    int u = (t >= o) ? s[t-o] : 0;
    __syncthreads();
    s[t] += u;
    __syncthreads();
  }
  wOff[b*B1 + t] = s[t] - v;
  if (t == B1-1) bucketCnt[b] = s[t];
}

// p1scatter with inline bucket-count scan (NB <= 256)
__global__ __launch_bounds__(256) void p1scatter_k(const int* __restrict__ src, const int* __restrict__ dst,
                                                   int E, int NB,
                                                   const int* __restrict__ bucketCnt,
                                                   const int* __restrict__ wOff,
                                                   int* __restrict__ bucketEdges){
  extern __shared__ int curs[];          // NB ints
  __shared__ int sb[256];
  int blk = blockIdx.x, t = threadIdx.x;
  int v = (t < NB) ? bucketCnt[t] : 0;
  sb[t] = v; __syncthreads();
  for (int o = 1; o < 256; o <<= 1){
    int u = (t >= o) ? sb[t-o] : 0;
    __syncthreads();
    sb[t] += u;
    __syncthreads();
  }
  if (t < NB) curs[t] = (sb[t] - v) + wOff[t*B1 + blk];
  __syncthreads();
  int CH = (E + B1 - 1) / B1;
  int lo = blk*CH, hi = min(E, lo + CH);
  for (int i = lo + t; i < hi; i += 256){
    int dd = dst[i];
    int b = dd >> BW_LOG;
    int pos = atomicAdd(&curs[b], 1);
    bucketEdges[pos] = (src[i] << BW_LOG) | (dd & (BWIDTH-1));
  }
}

// p2 with inline bucket-count scan; also writes off[N]
__global__ __launch_bounds__(BWIDTH) void p2_k(const int* __restrict__ bucketEdges,
                                               const int* __restrict__ bucketCnt, int NB,
                                               int* __restrict__ off, int* __restrict__ csr, int N){
  __shared__ int deg[BWIDTH];
  __shared__ int s[BWIDTH];
  __shared__ int cur[BWIDTH];
  __shared__ int sb[BWIDTH];
  int b = blockIdx.x, t = threadIdx.x;
  int vc = (t < NB) ? bucketCnt[t] : 0;
  sb[t] = vc; __syncthreads();
  for (int o = 1; o < BWIDTH; o <<= 1){
    int u = (t >= o) ? sb[t-o] : 0;
    __syncthreads();
    sb[t] += u;
    __syncthreads();
  }
  int e0 = (b > 0) ? sb[b-1] : 0;
  int e1 = sb[b];
  if (b == 0 && t == 0) off[N] = sb[NB-1];
  deg[t] = 0;
  __syncthreads();
  for (int i = e0 + t; i < e1; i += BWIDTH)
    atomicAdd(&deg[bucketEdges[i] & (BWIDTH-1)], 1);
  __syncthreads();
  int v = deg[t];
  s[t] = v; __syncthreads();
  for (int o = 1; o < BWIDTH; o <<= 1){
    int u = (t >= o) ? s[t-o] : 0;
    __syncthreads();
    s[t] += u;
    __syncthreads();
  }
  int excl = s[t] - v;
  int node = b*BWIDTH + t;
  if (node < N) off[node] = e0 + excl;
  cur[t] = excl;
  __syncthreads();
  for (int i = e0 + t; i < e1; i += BWIDTH){
    int pk = bucketEdges[i];
    int p = atomicAdd(&cur[pk & (BWIDTH-1)], 1);
    csr[e0 + p] = pk >> BW_LOG;
  }
}

// ---------------- W1T: [256][128] fp32 -> [128][256] bf16 ----------------
__global__ __launch_bounds__(256) void wt_k(const float* __restrict__ W, unsigned short* __restrict__ WT){
  int n = blockIdx.x;       // 0..127
  int k = threadIdx.x;      // 0..255
  WT[n*FIN + k] = f2bf(W[(size_t)k*D1 + n]);
}

// ---------------- W2T: [128][40] fp32 -> [48][128] bf16 ----------------
__global__ __launch_bounds__(128) void wt2_k(const float* __restrict__ W2, unsigned short* __restrict__ W2T){
  int c = blockIdx.x;       // 0..47
  int k = threadIdx.x;      // 0..127
  float v = (c < D2) ? W2[(size_t)k*D2 + c] : 0.f;
  W2T[c*D1 + k] = f2bf(v);
}

// ---------------- GEMM1 via MFMA ----------------
__global__ __launch_bounds__(256) void gemm1_mfma(const float* __restrict__ x,
    const unsigned short* __restrict__ W1T,
    const float* __restrict__ attS, const float* __restrict__ attD,
    unsigned short* __restrict__ h1b, float* __restrict__ aS, float* __restrict__ aD, int N){
  int tid = threadIdx.x;
  int w = tid >> 6, lane = tid & 63;
  int lr = lane & 15, lg = lane >> 4;
  int wm = w >> 1, wn = w & 1;
  int m0 = blockIdx.x * 64;

  int rowA[2];
  #pragma unroll
  for (int mi=0;mi<2;mi++){
    int r = m0 + wm*32 + mi*16 + lr;
    rowA[mi] = (r < N) ? r : (N-1);
  }

  f32x4 acc[2][4];
  #pragma unroll
  for (int mi=0;mi<2;mi++)
    #pragma unroll
    for (int ni=0;ni<4;ni++) acc[mi][ni] = (f32x4){0.f,0.f,0.f,0.f};

  #pragma unroll
  for (int ks = 0; ks < 8; ++ks){
    int k0 = ks*32 + lg*8;
    bf16x8 a[2], b[4];
    #pragma unroll
    for (int mi=0;mi<2;mi++){
      const float* px = x + (size_t)rowA[mi]*FIN + k0;
      float4 v0 = *(const float4*)px;
      float4 v1 = *(const float4*)(px+4);
      a[mi] = pack_bf8(v0, v1);
    }
    #pragma unroll
    for (int ni=0;ni<4;ni++){
      int col = wn*64 + ni*16 + lr;
      b[ni] = *(const bf16x8*)(W1T + (size_t)col*FIN + k0);
    }
    #pragma unroll
    for (int mi=0;mi<2;mi++)
      #pragma unroll
      for (int ni=0;ni<4;ni++)
        acc[mi][ni] = __builtin_amdgcn_mfma_f32_16x16x32_bf16(a[mi], b[ni], acc[mi][ni], 0, 0, 0);
  }

  #pragma unroll
  for (int mi=0;mi<2;mi++){
    #pragma unroll
    for (int ni=0;ni<4;ni++){
      int h = wn*4 + ni;
      int col = wn*64 + ni*16 + lr;
      float sS = attS[h*C1 + lr], sD = attD[h*C1 + lr];
      #pragma unroll
      for (int i=0;i<4;i++){
        int row = m0 + wm*32 + mi*16 + 4*lg + i;
        float v = acc[mi][ni][i];
        float pS = v*sS, pD = v*sD;
        pS += __shfl_xor(pS, 1); pD += __shfl_xor(pD, 1);
        pS += __shfl_xor(pS, 2); pD += __shfl_xor(pD, 2);
        pS += __shfl_xor(pS, 4); pD += __shfl_xor(pD, 4);
        pS += __shfl_xor(pS, 8); pD += __shfl_xor(pD, 8);
        if (row < N){
          h1b[(size_t)row*D1 + col] = f2bf(v);
          if (lr == 0){ aS[row*H1 + h] = pS; aD[row*H1 + h] = pD; }
        }
      }
    }
  }
}

// ---------------- GEMM2 via MFMA, pure bf16 ----------------
__global__ __launch_bounds__(256) void gemm2_mfma(const unsigned short* __restrict__ x2b,
    const unsigned short* __restrict__ W2T,
    const float* __restrict__ attS2, const float* __restrict__ attD2,
    unsigned short* __restrict__ h2b, float* __restrict__ aS2, float* __restrict__ aD2, int N){
  int tid = threadIdx.x;
  int w = tid >> 6, lane = tid & 63;
  int lr = lane & 15, lg = lane >> 4;
  int m0 = blockIdx.x*128 + w*32;

  int rowA[2];
  #pragma unroll
  for (int mi=0;mi<2;mi++){
    int r = m0 + mi*16 + lr;
    rowA[mi] = (r < N) ? r : (N-1);
  }

  f32x4 acc[2][3];
  #pragma unroll
  for (int mi=0;mi<2;mi++)
    #pragma unroll
    for (int ni=0;ni<3;ni++) acc[mi][ni] = (f32x4){0.f,0.f,0.f,0.f};

  #pragma unroll
  for (int ks = 0; ks < 4; ++ks){
    int k0 = ks*32 + lg*8;
    bf16x8 a[2], b[3];
    #pragma unroll
    for (int mi=0;mi<2;mi++)
      a[mi] = *(const bf16x8*)(x2b + (size_t)rowA[mi]*D1 + k0);
    #pragma unroll
    for (int ni=0;ni<3;ni++){
      int col = ni*16 + lr;
      b[ni] = *(const bf16x8*)(W2T + (size_t)col*D1 + k0);
    }
    #pragma unroll
    for (int mi=0;mi<2;mi++)
      #pragma unroll
      for (int ni=0;ni<3;ni++)
        acc[mi][ni] = __builtin_amdgcn_mfma_f32_16x16x32_bf16(a[mi], b[ni], acc[mi][ni], 0, 0, 0);
  }

  float attSv[3], attDv[3];
  #pragma unroll
  for (int ni=0;ni<3;ni++){
    int col = ni*16 + lr;
    attSv[ni] = (col < D2) ? attS2[col] : 0.f;
    attDv[ni] = (col < D2) ? attD2[col] : 0.f;
  }
  #pragma unroll
  for (int mi=0;mi<2;mi++){
    #pragma unroll
    for (int i=0;i<4;i++){
      int row = m0 + mi*16 + 4*lg + i;
      float pS = 0.f, pD = 0.f;
      #pragma unroll
      for (int ni=0;ni<3;ni++){
        pS += acc[mi][ni][i]*attSv[ni];
        pD += acc[mi][ni][i]*attDv[ni];
      }
      pS += __shfl_xor(pS, 1); pD += __shfl_xor(pD, 1);
      pS += __shfl_xor(pS, 2); pD += __shfl_xor(pD, 2);
      pS += __shfl_xor(pS, 4); pD += __shfl_xor(pD, 4);
      pS += __shfl_xor(pS, 8); pD += __shfl_xor(pD, 8);
      if (row < N){
        #pragma unroll
        for (int ni=0;ni<3;ni++){
          int col = ni*16 + lr;
          if (col < D2) h2b[(size_t)row*D2 + col] = f2bf(acc[mi][ni][i]);
        }
        if (lr == 0){ aS2[row] = pS; aD2[row] = pD; }
      }
    }
  }
}

// ---------------- node1: 4 ch/lane, 2 edges per wave-iteration ----------------
__global__ __launch_bounds__(64) void node1_k(const unsigned short* __restrict__ h1b,
    const float* __restrict__ aS, const float* __restrict__ aD,
    const int* __restrict__ off, const int* __restrict__ csr,
    const float* __restrict__ b1, unsigned short* __restrict__ x2b, int N){
  int n = blockIdx.x;
  int lane = threadIdx.x;
  int half = lane >> 5, l32 = lane & 31;
  int c = l32*4;                  // channels c..c+3
  int h = l32 >> 2;               // head
  float ad = aD[n*H1+h];
  float d = 0.f, a0 = 0.f, a1 = 0.f, a2 = 0.f, a3 = 0.f;
  if (half == 0){                 // self loop on half 0
    float p = __expf(lrelu(aS[n*H1+h] + ad));
    uint2 hv = *(const uint2*)&h1b[(size_t)n*D1 + c];
    d = p;
    a0 = p*bf_lo(hv.x); a1 = p*bf_hi(hv.x);
    a2 = p*bf_lo(hv.y); a3 = p*bf_hi(hv.y);
  }
  int e = off[n+1];
  int i = off[n] + half;
  for (; i + 6 < e; i += 8){      // 4 edges per half per iter
    int s0=csr[i], s1=csr[i+2], s2=csr[i+4], s3=csr[i+6];
    float e0=aS[s0*H1+h], e1=aS[s1*H1+h], e2=aS[s2*H1+h], e3=aS[s3*H1+h];
    uint2 v0 = *(const uint2*)&h1b[(size_t)s0*D1+c];
    uint2 v1 = *(const uint2*)&h1b[(size_t)s1*D1+c];
    uint2 v2 = *(const uint2*)&h1b[(size_t)s2*D1+c];
    uint2 v3 = *(const uint2*)&h1b[(size_t)s3*D1+c];
    float p0=__expf(lrelu(e0+ad)), p1=__expf(lrelu(e1+ad));
    float p2=__expf(lrelu(e2+ad)), p3=__expf(lrelu(e3+ad));
    d += p0+p1+p2+p3;
    a0 += p0*bf_lo(v0.x)+p1*bf_lo(v1.x)+p2*bf_lo(v2.x)+p3*bf_lo(v3.x);
    a1 += p0*bf_hi(v0.x)+p1*bf_hi(v1.x)+p2*bf_hi(v2.x)+p3*bf_hi(v3.x);
    a2 += p0*bf_lo(v0.y)+p1*bf_lo(v1.y)+p2*bf_lo(v2.y)+p3*bf_lo(v3.y);
    a3 += p0*bf_hi(v0.y)+p1*bf_hi(v1.y)+p2*bf_hi(v2.y)+p3*bf_hi(v3.y);
  }
  for (; i < e; i += 2){
    int s = csr[i];
    float pp = __expf(lrelu(aS[s*H1+h] + ad));
    uint2 vv = *(const uint2*)&h1b[(size_t)s*D1 + c];
    d += pp;
    a0 += pp*bf_lo(vv.x); a1 += pp*bf_hi(vv.x);
    a2 += pp*bf_lo(vv.y); a3 += pp*bf_hi(vv.y);
  }
  d  += __shfl_xor(d, 32);
  a0 += __shfl_xor(a0, 32); a1 += __shfl_xor(a1, 32);
  a2 += __shfl_xor(a2, 32); a3 += __shfl_xor(a3, 32);
  if (half == 0){
    float inv = 1.f/d;
    float o0 = elu(a0*inv + b1[c]);
    float o1 = elu(a1*inv + b1[c+1]);
    float o2 = elu(a2*inv + b1[c+2]);
    float o3 = elu(a3*inv + b1[c+3]);
    uint2 pk;
    pk.x = (unsigned)f2bf(o0) | ((unsigned)f2bf(o1) << 16);
    pk.y = (unsigned)f2bf(o2) | ((unsigned)f2bf(o3) << 16);
    *(uint2*)&x2b[(size_t)n*D1 + c] = pk;
  }
}

// ---------------- node2: 4 ch/lane, 4 edges per wave-iteration ----------------
__global__ __launch_bounds__(64) void node2_k(const unsigned short* __restrict__ h2b,
    const float* __restrict__ aS2, const float* __restrict__ aD2,
    const int* __restrict__ off, const int* __restrict__ csr,
    const float* __restrict__ b2, float* __restrict__ out, int N){
  int n = blockIdx.x;
  int lane = threadIdx.x;
  int g = lane >> 4, l16 = lane & 15;
  int c = l16*4;                  // channels c..c+3 (l16<10 active)
  bool act = l16 < 10;
  float ad = aD2[n];
  float d = 0.f, a0 = 0.f, a1 = 0.f, a2 = 0.f, a3 = 0.f;
  if (g == 0){                    // self loop on group 0
    float p = __expf(lrelu(aS2[n] + ad));
    d = p;
    if (act){
      uint2 v = *(const uint2*)&h2b[(size_t)n*D2 + c];
      a0 = p*bf_lo(v.x); a1 = p*bf_hi(v.x);
      a2 = p*bf_lo(v.y); a3 = p*bf_hi(v.y);
    }
  }
  int e = off[n+1];
  int i = off[n] + g;
  for (; i + 12 < e; i += 16){    // 4 edges per group per iter
    int s0=csr[i], s1=csr[i+4], s2=csr[i+8], s3=csr[i+12];
    float e0=aS2[s0], e1=aS2[s1], e2=aS2[s2], e3=aS2[s3];
    uint2 v0, v1, v2, v3;
    if (act){
      v0 = *(const uint2*)&h2b[(size_t)s0*D2+c];
      v1 = *(const uint2*)&h2b[(size_t)s1*D2+c];
      v2 = *(const uint2*)&h2b[(size_t)s2*D2+c];
      v3 = *(const uint2*)&h2b[(size_t)s3*D2+c];
    } else { v0=v1=v2=v3=make_uint2(0u,0u); }
    float p0=__expf(lrelu(e0+ad)), p1=__expf(lrelu(e1+ad));
    float p2=__expf(lrelu(e2+ad)), p3=__expf(lrelu(e3+ad));
    d += p0+p1+p2+p3;
    a0 += p0*bf_lo(v0.x)+p1*bf_lo(v1.x)+p2*bf_lo(v2.x)+p3*bf_lo(v3.x);
    a1 += p0*bf_hi(v0.x)+p1*bf_hi(v1.x)+p2*bf_hi(v2.x)+p3*bf_hi(v3.x);
    a2 += p0*bf_lo(v0.y)+p1*bf_lo(v1.y)+p2*bf_lo(v2.y)+p3*bf_lo(v3.y);
    a3 += p0*bf_hi(v0.y)+p1*bf_hi(v1.y)+p2*bf_hi(v2.y)+p3*bf_hi(v3.y);
  }
  for (; i < e; i += 4){
    int s = csr[i];
    float pp = __expf(lrelu(aS2[s] + ad));
    d += pp;
    if (act){
      uint2 vv = *(const uint2*)&h2b[(size_t)s*D2 + c];
      a0 += pp*bf_lo(vv.x); a1 += pp*bf_hi(vv.x);
      a2 += pp*bf_lo(vv.y); a3 += pp*bf_hi(vv.y);
    }
  }
  d  += __shfl_xor(d, 16);  d  += __shfl_xor(d, 32);
  a0 += __shfl_xor(a0, 16); a0 += __shfl_xor(a0, 32);
  a1 += __shfl_xor(a1, 16); a1 += __shfl_xor(a1, 32);
  a2 += __shfl_xor(a2, 16); a2 += __shfl_xor(a2, 32);
  a3 += __shfl_xor(a3, 16); a3 += __shfl_xor(a3, 32);
  if (g == 0 && act){
    float inv = 1.f/d;
    float4 o;
    o.x = a0*inv + b2[c];
    o.y = a1*inv + b2[c+1];
    o.z = a2*inv + b2[c+2];
    o.w = a3*inv + b2[c+3];
    *(float4*)&out[(size_t)n*D2 + c] = o;
  }
}

extern "C" void kernel_launch(void* const* d_in, const int* in_sizes, int n_in,
                              void* d_out, int out_size, void* d_ws, size_t ws_size,
                              hipStream_t stream){
  const float* x     = (const float*)d_in[0];
  const int*   ei    = (const int*)d_in[1];
  const float* W1    = (const float*)d_in[2];
  const float* attS1 = (const float*)d_in[3];
  const float* attD1 = (const float*)d_in[4];
  const float* b1    = (const float*)d_in[5];
  const float* W2    = (const float*)d_in[6];
  const float* attS2 = (const float*)d_in[7];
  const float* attD2 = (const float*)d_in[8];
  const float* b2    = (const float*)d_in[9];
  float* out = (float*)d_out;

  int N = in_sizes[0] / FIN;   // 50000
  int E = in_sizes[1] / 2;     // 1600000
  const int* src = ei;
  const int* dst = ei + E;
  int NB = (N + BWIDTH - 1) >> BW_LOG;    // 196

  char* ws = (char*)d_ws;
  size_t o = 0;
  auto alloc = [&](size_t bytes) -> void* {
    void* p = ws + o;
    o += (bytes + 255) & ~size_t(255);
    return p;
  };
  unsigned short* h1b = (unsigned short*)alloc((size_t)N*D1*sizeof(unsigned short));
  unsigned short* x2b = (unsigned short*)alloc((size_t)N*D1*sizeof(unsigned short));
  unsigned short* h2b = (unsigned short*)alloc((size_t)N*D2*sizeof(unsigned short));
  float* aS1   = (float*)alloc((size_t)N*H1*sizeof(float));
  float* aD1   = (float*)alloc((size_t)N*H1*sizeof(float));
  float* aS2   = (float*)alloc((size_t)N*sizeof(float));
  float* aD2   = (float*)alloc((size_t)N*sizeof(float));
  int*   off   = (int*)alloc((size_t)(N+1)*sizeof(int));
  int*   csr   = (int*)alloc((size_t)E*sizeof(int));
  int*   blockHist   = (int*)alloc((size_t)NB*B1*sizeof(int));
  int*   wOff        = (int*)alloc((size_t)NB*B1*sizeof(int));
  int*   bucketCnt   = (int*)alloc((size_t)NB*sizeof(int));
  int*   bucketEdges = (int*)alloc((size_t)E*sizeof(int));
  unsigned short* W1T = (unsigned short*)alloc((size_t)D1*FIN*sizeof(unsigned short));
  unsigned short* W2T = (unsigned short*)alloc((size_t)D2P*D1*sizeof(unsigned short));

  size_t smNB = (size_t)NB*sizeof(int);
  p1count_k<<<B1, 256, smNB, stream>>>(dst, E, NB, blockHist);
  bscan_k<<<NB, B1, 0, stream>>>(blockHist, wOff, bucketCnt);
  p1scatter_k<<<B1, 256, smNB, stream>>>(src, dst, E, NB, bucketCnt, wOff, bucketEdges);
  p2_k<<<NB, BWIDTH, 0, stream>>>(bucketEdges, bucketCnt, NB, off, csr, N);
  wt_k<<<D1, 256, 0, stream>>>(W1, W1T);
  wt2_k<<<D2P, 128, 0, stream>>>(W2, W2T);
  gemm1_mfma<<<(N+63)/64, 256, 0, stream>>>(x, W1T, attS1, attD1, h1b, aS1, aD1, N);
  node1_k<<<N, 64, 0, stream>>>(h1b, aS1, aD1, off, csr, b1, x2b, N);
  gemm2_mfma<<<(N+127)/128, 256, 0, stream>>>(x2b, W2T, attS2, attD2, h2b, aS2, aD2, N);
  node2_k<<<N, 64, 0, stream>>>(h2b, aS2, aD2, off, csr, b2, out, N);
}